// Round 4
// baseline (217.996 us; speedup 1.0000x reference)
//
#include <hip/hip_runtime.h>
#include <hip/hip_bf16.h>

// Combine: out[b,:] = branches[argmax(gate[b,:4])][b,:]
// B=4096 rows, D=4096 fp32, N=4 branches. Pure select-copy, memory-bound.
//
// R4: the compiler kept collapsing the load batch to 1 float4 in flight
// (VGPR_Count=12 in R3 — load/wait/store chains, latency-serialized at
// 2.4 TB/s while the memset kernel hits 6.4 TB/s). Force 8-deep MLP:
// 2 rows per block, 8 loads issued before a sched_barrier(0), then 8
// nontemporal stores. Values live across the barrier pin 32 data VGPRs.

#define B 4096
#define D 4096

typedef float fvec4 __attribute__((ext_vector_type(4)));

__device__ __forceinline__ int argmax4(fvec4 g) {
    int idx = 0;
    float best = g.x;
    if (g.y > best) { best = g.y; idx = 1; }
    if (g.z > best) { best = g.z; idx = 2; }
    if (g.w > best) { best = g.w; idx = 3; }
    return idx;
}

__global__ __launch_bounds__(256) void combine_kernel(
    const float* __restrict__ b0, const float* __restrict__ b1,
    const float* __restrict__ b2, const float* __restrict__ b3,
    const float* __restrict__ gate, float* __restrict__ out) {

    const int r0 = blockIdx.x * 2;
    const int r1 = r0 + 1;
    const int t  = threadIdx.x;

    // Both gate rows: adjacent float4s, one round trip for the pair.
    fvec4 g0 = ((const fvec4*)gate)[r0];
    fvec4 g1 = ((const fvec4*)gate)[r1];

    const int i0 = argmax4(g0);
    const int i1 = argmax4(g1);

    const float* s0 = (i0 == 0) ? b0 : (i0 == 1) ? b1 : (i0 == 2) ? b2 : b3;
    const float* s1 = (i1 == 0) ? b0 : (i1 == 1) ? b1 : (i1 == 2) ? b2 : b3;

    const fvec4* sa = (const fvec4*)(s0 + (size_t)r0 * D);
    const fvec4* sb = (const fvec4*)(s1 + (size_t)r1 * D);
    fvec4*       da = (fvec4*)(out + (size_t)r0 * D);
    fvec4*       db = (fvec4*)(out + (size_t)r1 * D);

    // 8 independent 16B loads — all issued before any store (barrier below).
    fvec4 v0 = sa[t];
    fvec4 v1 = sa[t + 256];
    fvec4 v2 = sa[t + 512];
    fvec4 v3 = sa[t + 768];
    fvec4 w0 = sb[t];
    fvec4 w1 = sb[t + 256];
    fvec4 w2 = sb[t + 512];
    fvec4 w3 = sb[t + 768];

    // Nothing may cross: loads stay grouped above, stores below.
    __builtin_amdgcn_sched_barrier(0);

    __builtin_nontemporal_store(v0, &da[t]);
    __builtin_nontemporal_store(v1, &da[t + 256]);
    __builtin_nontemporal_store(v2, &da[t + 512]);
    __builtin_nontemporal_store(v3, &da[t + 768]);
    __builtin_nontemporal_store(w0, &db[t]);
    __builtin_nontemporal_store(w1, &db[t + 256]);
    __builtin_nontemporal_store(w2, &db[t + 512]);
    __builtin_nontemporal_store(w3, &db[t + 768]);
}

extern "C" void kernel_launch(void* const* d_in, const int* in_sizes, int n_in,
                              void* d_out, int out_size, void* d_ws, size_t ws_size,
                              hipStream_t stream) {
    const float* b0   = (const float*)d_in[0];
    const float* b1   = (const float*)d_in[1];
    const float* b2   = (const float*)d_in[2];
    const float* b3   = (const float*)d_in[3];
    const float* gate = (const float*)d_in[4];
    float* out = (float*)d_out;

    combine_kernel<<<B / 2, 256, 0, stream>>>(b0, b1, b2, b3, gate, out);
}